// Round 9
// baseline (134.868 us; speedup 1.0000x reference)
//
#include <hip/hip_runtime.h>
#include <math.h>

#define RED_BLOCKS 256
#define SB 2048            // scatter blocks
#define NT 256             // scatter threads per block (exactly 4 waves)
#define NW 4               // waves per scatter block
#define MAXCOL 64          // ctrl array size (cursors + spill cursor at [63])
#define ASH 12
#define ACH (1 << ASH)     // 4096 nodes per bin
#define AKS 16             // reduce sub-blocks per column
#define REDT 512           // reduce threads per block
#define CAPA (1u << 18)    // per-column capacity (mean 256K + ~12 sigma)
#define SPILLCAP (1u << 20)
#define ORD_OFF 0x007fffffu  // f2ord_raw(-inf); shifted so 0 == "-inf"

// Monotone order-preserving float->uint mapping, shifted so 0 means -inf.
__device__ __forceinline__ unsigned f2ord(float f) {
    unsigned u = __float_as_uint(f);
    u = (u & 0x80000000u) ? ~u : (u | 0x80000000u);
    return u - ORD_OFF;
}
__device__ __forceinline__ float ord2f(unsigned uo) {
    unsigned u = uo + ORD_OFF;
    unsigned v = (u & 0x80000000u) ? (u & 0x7fffffffu) : ~u;
    return __uint_as_float(v);
}

// Identical edge-slice iteration for both scatter passes (must match exactly).
template <class F>
__device__ __forceinline__ void for_each_edge(const int* __restrict__ src,
                                              const int* __restrict__ dst,
                                              int s0, int s1, F f) {
    for (int i = s0 + threadIdx.x * 4; i < s1; i += blockDim.x * 4) {
        if (i + 3 < s1) {
            int4 a = *(const int4*)(src + i);
            int4 b = *(const int4*)(dst + i);
            f(a.x, b.x); f(a.y, b.y); f(a.z, b.z); f(a.w, b.w);
        } else {
            for (int j = i; j < s1 && j < i + 4; ++j) f(src[j], dst[j]);
        }
    }
}

__device__ __forceinline__ void h_row_body(const float* __restrict__ loss,
                                           const float* __restrict__ Ws,
                                           float* __restrict__ h, int n, int blk) {
    int sub = threadIdx.x & 15, r = threadIdx.x >> 4;
    int row = blk * 16 + r;
    if (row >= n) return;
    const float4* f4 = (const float4*)(loss + (size_t)row * 200);
    const float4* W4 = (const float4*)Ws;
    float4 a, w;
    float acc = 0.0f;
    a = f4[sub];      w = W4[sub];      acc += a.x*w.x + a.y*w.y + a.z*w.z + a.w*w.w;
    a = f4[sub + 16]; w = W4[sub + 16]; acc += a.x*w.x + a.y*w.y + a.z*w.z + a.w*w.w;
    a = f4[sub + 32]; w = W4[sub + 32]; acc += a.x*w.x + a.y*w.y + a.z*w.z + a.w*w.w;
    if (sub < 2) { a = f4[48 + sub]; w = W4[48 + sub]; acc += a.x*w.x + a.y*w.y + a.z*w.z + a.w*w.w; }
    #pragma unroll
    for (int off = 8; off > 0; off >>= 1) acc += __shfl_down(acc, off, 16);
    if (sub == 0) h[row] = acc;
}

// h + control-word init (block 0 zeroes the cursors; visible at kernel boundary).
__global__ void k_h(const float* __restrict__ loss, const float* __restrict__ Ws,
                    float* __restrict__ h, unsigned* __restrict__ ctrl, int n) {
    if (blockIdx.x == 0 && threadIdx.x < MAXCOL) ctrl[threadIdx.x] = 0u;
    h_row_body(loss, Ws, h, n, blockIdx.x);
}

// Two-pass scatter with wave-private cursors:
//   pass 1: per-WAVE LDS histograms (cnt[w][col]).
//   reserve: ONE global atomicAdd per (block,col) of the block total; per-wave
//            bases derived in LDS -> cross-wave atomic collisions are zero.
//   pass 2: re-read slice (L2-hot), bump wave-private cursor, write entry.
// Bucket fill order is nondeterministic; per-column CONTENT is a fixed set ->
// max-reduce is exact and deterministic.
__global__ void k_scatter(const int* __restrict__ src, const int* __restrict__ dst,
                          const float* __restrict__ h, unsigned* __restrict__ ctrl,
                          uint2* __restrict__ buckets, uint2* __restrict__ spill,
                          int ne, int nbin, int epb) {
    __shared__ unsigned cnt[NW * MAXCOL];
    __shared__ unsigned curw[NW * MAXCOL];
    int ncol = 2 * nbin;
    int wv = threadIdx.x >> 6;
    for (int t = threadIdx.x; t < NW * ncol; t += blockDim.x) cnt[t] = 0u;
    __syncthreads();
    int s0 = blockIdx.x * epb, s1 = min(s0 + epb, ne);
    unsigned* myh = cnt + wv * ncol;
    for_each_edge(src, dst, s0, s1, [&](int s, int d) {
        if (s != d) {
            atomicAdd(&myh[d >> ASH], 1u);
            atomicAdd(&myh[nbin + (s >> ASH)], 1u);
        }
    });
    __syncthreads();
    if (threadIdx.x < (unsigned)ncol) {
        int t = threadIdx.x;
        unsigned c0 = cnt[0 * ncol + t], c1 = cnt[1 * ncol + t];
        unsigned c2 = cnt[2 * ncol + t], c3 = cnt[3 * ncol + t];
        unsigned tot = c0 + c1 + c2 + c3;
        unsigned base = tot ? atomicAdd(&ctrl[t], tot) : 0u;  // column-local base
        curw[0 * ncol + t] = base;
        curw[1 * ncol + t] = base + c0;
        curw[2 * ncol + t] = base + c0 + c1;
        curw[3 * ncol + t] = base + c0 + c1 + c2;
    }
    __syncthreads();
    unsigned* myc = curw + wv * ncol;
    for_each_edge(src, dst, s0, s1, [&](int s, int d) {
        if (s != d) {
            unsigned hs = f2ord(h[s]);
            unsigned hd = f2ord(h[d]);
            int c0 = d >> ASH;
            unsigned p0 = atomicAdd(&myc[c0], 1u);
            if (p0 < CAPA) buckets[(size_t)c0 * CAPA + p0] = make_uint2((unsigned)d, hs);
            else { unsigned sp = atomicAdd(&ctrl[MAXCOL - 1], 1u);
                   if (sp < SPILLCAP) spill[sp] = make_uint2((unsigned)d, hs); }
            int c1 = nbin + (s >> ASH);
            unsigned p1 = atomicAdd(&myc[c1], 1u);
            if (p1 < CAPA) buckets[(size_t)c1 * CAPA + p1] = make_uint2((unsigned)s | (1u << 24), hd);
            else { unsigned sp = atomicAdd(&ctrl[MAXCOL - 1], 1u);
                   if (sp < SPILLCAP) spill[sp] = make_uint2((unsigned)s | (1u << 24), hd); }
        }
    });
}

// One WG per (col, ks): stream a 1/AKS slice of the dense column (4 loads in
// flight, 512 threads), 16KB LDS max, write an ACH-word partial.
__global__ void k_reduce(const uint2* __restrict__ buckets, const unsigned* __restrict__ ctrl,
                         const uint2* __restrict__ spill, unsigned* __restrict__ partials,
                         int nbin) {
    __shared__ unsigned lds[ACH];
    int col = blockIdx.x / AKS, ks = blockIdx.x - col * AKS;
    for (int t = threadIdx.x; t < ACH; t += blockDim.x) lds[t] = 0u;
    __syncthreads();
    unsigned len = min(ctrl[col], CAPA);
    unsigned a = (unsigned)(((unsigned long long)len * ks) / AKS);
    unsigned b = (unsigned)(((unsigned long long)len * (ks + 1)) / AKS);
    const uint2* cb = buckets + (size_t)col * CAPA;
    unsigned i = a + threadIdx.x;
    for (; i + 3u * REDT < b; i += 4u * REDT) {   // 4 independent loads in flight
        uint2 e0 = cb[i];
        uint2 e1 = cb[i + REDT];
        uint2 e2 = cb[i + 2u * REDT];
        uint2 e3 = cb[i + 3u * REDT];
        atomicMax(&lds[e0.x & (ACH - 1)], e0.y);
        atomicMax(&lds[e1.x & (ACH - 1)], e1.y);
        atomicMax(&lds[e2.x & (ACH - 1)], e2.y);
        atomicMax(&lds[e3.x & (ACH - 1)], e3.y);
    }
    for (; i < b; i += REDT) {
        uint2 e = cb[i];
        atomicMax(&lds[e.x & (ACH - 1)], e.y);
    }
    if (ks == 0) {  // spill entries (normally zero)
        unsigned sc = min(ctrl[MAXCOL - 1], (unsigned)SPILLCAP);
        for (unsigned j = threadIdx.x; j < sc; j += blockDim.x) {
            uint2 e = spill[j];
            unsigned node = e.x & 0x00FFFFFFu, dir = e.x >> 24;
            if ((int)(dir * nbin + (node >> ASH)) == col)
                atomicMax(&lds[node & (ACH - 1)], e.y);
        }
    }
    __syncthreads();
    unsigned* outp = partials + (size_t)blockIdx.x * ACH;
    for (int t = threadIdx.x; t < ACH; t += blockDim.x) outp[t] = lds[t];
}

// ---- Fallback: device-scope filtered atomics ----
__global__ void k_edges_dev(const int* __restrict__ src, const int* __restrict__ dst,
                            const float* __restrict__ h, unsigned* __restrict__ partials, int ne) {
    int e = blockIdx.x * blockDim.x + threadIdx.x;
    if (e >= ne) return;
    int s = src[e], d = dst[e];
    if (s == d) return;
    unsigned hs = f2ord(h[s]);
    unsigned hd = f2ord(h[d]);
    unsigned* slot0 = &partials[d];
    unsigned* slot1 = &partials[(1 << 17) + s];
    if (*slot0 < hs) atomicMax(slot0, hs);
    if (*slot1 < hd) atomicMax(slot1, hd);
}

// Fold ks x 2 partials, logit = h + w0*pre + w1*suc (0 == empty -> 0.0 fill),
// block-partial max (fixed RED_BLOCKS grid).
__global__ void k_logit_max(const float* __restrict__ h, const unsigned* __restrict__ partials,
                            const float* __restrict__ Wg, float* __restrict__ logit,
                            float* __restrict__ maxPart, int n, int nbin, int ks, int shift) {
    __shared__ float sm[256];
    float w0 = Wg[0], w1 = Wg[1];
    unsigned mask = (1u << shift) - 1;
    size_t CH = (size_t)1 << shift;
    float m = -INFINITY;
    for (int i = blockIdx.x * 256 + threadIdx.x; i < n; i += 256 * RED_BLOCKS) {
        int chunk = i >> shift, off = i & mask;
        size_t b0 = ((size_t)chunk * ks) * CH + off;
        size_t b1 = ((size_t)(nbin + chunk) * ks) * CH + off;
        unsigned p = 0, s = 0;
        #pragma unroll 4
        for (int k = 0; k < ks; ++k) {
            p = max(p, partials[b0 + (size_t)k * CH]);
            s = max(s, partials[b1 + (size_t)k * CH]);
        }
        float pf = p ? ord2f(p) : 0.0f;
        float sf = s ? ord2f(s) : 0.0f;
        float l = h[i] + w0 * pf + w1 * sf;
        logit[i] = l;
        m = fmaxf(m, l);
    }
    sm[threadIdx.x] = m;
    __syncthreads();
    for (int off = 128; off > 0; off >>= 1) {
        if (threadIdx.x < off) sm[threadIdx.x] = fmaxf(sm[threadIdx.x], sm[threadIdx.x + off]);
        __syncthreads();
    }
    if (threadIdx.x == 0) maxPart[blockIdx.x] = sm[0];
}

__global__ void k_exp_sum(const float* __restrict__ logit, const float* __restrict__ maxPart,
                          float* __restrict__ out, float* __restrict__ sumPart, int n) {
    __shared__ float sm[256];
    sm[threadIdx.x] = maxPart[threadIdx.x];
    __syncthreads();
    for (int off = 128; off > 0; off >>= 1) {
        if (threadIdx.x < off) sm[threadIdx.x] = fmaxf(sm[threadIdx.x], sm[threadIdx.x + off]);
        __syncthreads();
    }
    float gmax = sm[0];
    __syncthreads();
    float acc = 0.0f;
    for (int i = blockIdx.x * 256 + threadIdx.x; i < n; i += 256 * RED_BLOCKS) {
        float e = expf(logit[i] - gmax);
        out[i] = e;
        acc += e;
    }
    sm[threadIdx.x] = acc;
    __syncthreads();
    for (int off = 128; off > 0; off >>= 1) {
        if (threadIdx.x < off) sm[threadIdx.x] += sm[threadIdx.x + off];
        __syncthreads();
    }
    if (threadIdx.x == 0) sumPart[blockIdx.x] = sm[0];
}

__global__ void k_norm(const float* __restrict__ sumPart, float* __restrict__ out, int n) {
    __shared__ float sm[256];
    sm[threadIdx.x] = sumPart[threadIdx.x];
    __syncthreads();
    for (int off = 128; off > 0; off >>= 1) {
        if (threadIdx.x < off) sm[threadIdx.x] += sm[threadIdx.x + off];
        __syncthreads();
    }
    float inv = 1.0f / sm[0];
    for (int i = blockIdx.x * 256 + threadIdx.x; i < n; i += 256 * RED_BLOCKS) out[i] *= inv;
}

extern "C" void kernel_launch(void* const* d_in, const int* in_sizes, int n_in,
                              void* d_out, int out_size, void* d_ws, size_t ws_size,
                              hipStream_t stream) {
    const float* loss = (const float*)d_in[0];   // [N, 200]
    const float* Ws   = (const float*)d_in[1];   // [1, 200]
    const float* Wg   = (const float*)d_in[2];   // [1, 2]
    const int* esrc   = (const int*)d_in[3];     // [E]
    const int* edst   = (const int*)d_in[4];     // [E]
    float* out = (float*)d_out;                  // [N]

    const int n  = in_sizes[0] / 200;
    const int ne = in_sizes[3];
    const int epb = (((ne + SB - 1) / SB) + 3) & ~3;  // edges per block, x4 aligned
    const int Gh  = (n + 15) / 16;

    const int nbin = (n + ACH - 1) >> ASH, ncol = 2 * nbin;

    // ws layout (32-bit words):
    // h[n] | logit[n] | maxPart | sumPart | ctrl[64] | partials[ncol*AKS*ACH] |
    // buckets[ncol*CAPA*2] | spill[SPILLCAP*2]
    float*    h        = (float*)d_ws;
    float*    logit    = h + n;
    float*    maxPart  = logit + n;
    float*    sumPart  = maxPart + RED_BLOCKS;
    unsigned* ctrl     = (unsigned*)(sumPart + RED_BLOCKS);
    unsigned* partials = ctrl + MAXCOL;
    size_t part_w = (size_t)ncol * AKS * ACH;
    uint2*    buckets  = (uint2*)(partials + part_w);
    uint2*    spill    = buckets + (size_t)ncol * CAPA;
    size_t need = ((size_t)2 * n + 2 * RED_BLOCKS + MAXCOL + part_w) * 4
                + ((size_t)ncol * CAPA + SPILLCAP) * 8;

    k_h<<<Gh, 256, 0, stream>>>(loss, Ws, h, ctrl, n);

    if (need <= ws_size && ncol < MAXCOL) {
        k_scatter<<<SB, NT, 0, stream>>>(esrc, edst, h, ctrl, buckets, spill, ne, nbin, epb);
        k_reduce<<<ncol * AKS, REDT, 0, stream>>>(buckets, ctrl, spill, partials, nbin);
        k_logit_max<<<RED_BLOCKS, 256, 0, stream>>>(h, partials, Wg, logit, maxPart, n, nbin, AKS, ASH);
    } else {
        hipMemsetAsync(partials, 0, (size_t)2 * (1 << 17) * 4, stream);
        k_edges_dev<<<(ne + 255) / 256, 256, 0, stream>>>(esrc, edst, h, partials, ne);
        k_logit_max<<<RED_BLOCKS, 256, 0, stream>>>(h, partials, Wg, logit, maxPart, n, 1, 1, 17);
    }

    k_exp_sum<<<RED_BLOCKS, 256, 0, stream>>>(logit, maxPart, out, sumPart, n);
    k_norm<<<RED_BLOCKS, 256, 0, stream>>>(sumPart, out, n);
}

// Round 10
// 96.426 us; speedup vs baseline: 1.3987x; 1.3987x over previous
//
#include <hip/hip_runtime.h>
#include <math.h>

#define RED_BLOCKS 256
#define SB 1024            // scatter blocks
#define NT 512             // scatter threads per block
#define NW 8               // waves per scatter block (NT/64)
#define MAXCOL 32          // ctrl array size (cursors + spill cursor at [31])
#define ASH 13
#define ACH (1 << ASH)     // 8192 nodes per bin
#define AKS 16             // reduce sub-blocks per column
#define REDT 1024          // reduce threads per block
#define CAPA (1u << 19)    // per-column capacity (mean ~262K + slack)
#define SPILLCAP (1u << 20)
#define ORD_OFF 0x007fffffu  // f2ord_raw(-inf); shifted so 0 == "-inf"

// Monotone order-preserving float->uint mapping, shifted so 0 means -inf.
__device__ __forceinline__ unsigned f2ord(float f) {
    unsigned u = __float_as_uint(f);
    u = (u & 0x80000000u) ? ~u : (u | 0x80000000u);
    return u - ORD_OFF;
}
__device__ __forceinline__ float ord2f(unsigned uo) {
    unsigned u = uo + ORD_OFF;
    unsigned v = (u & 0x80000000u) ? (u & 0x7fffffffu) : ~u;
    return __uint_as_float(v);
}

// Identical edge-slice iteration for both scatter passes (must match exactly).
template <class F>
__device__ __forceinline__ void for_each_edge(const int* __restrict__ src,
                                              const int* __restrict__ dst,
                                              int s0, int s1, F f) {
    for (int i = s0 + threadIdx.x * 4; i < s1; i += blockDim.x * 4) {
        if (i + 3 < s1) {
            int4 a = *(const int4*)(src + i);
            int4 b = *(const int4*)(dst + i);
            f(a.x, b.x); f(a.y, b.y); f(a.z, b.z); f(a.w, b.w);
        } else {
            for (int j = i; j < s1 && j < i + 4; ++j) f(src[j], dst[j]);
        }
    }
}

__device__ __forceinline__ void h_row_body(const float* __restrict__ loss,
                                           const float* __restrict__ Ws,
                                           float* __restrict__ h, int n, int blk) {
    int sub = threadIdx.x & 15, r = threadIdx.x >> 4;
    int row = blk * 16 + r;
    if (row >= n) return;
    const float4* f4 = (const float4*)(loss + (size_t)row * 200);
    const float4* W4 = (const float4*)Ws;
    float4 a, w;
    float acc = 0.0f;
    a = f4[sub];      w = W4[sub];      acc += a.x*w.x + a.y*w.y + a.z*w.z + a.w*w.w;
    a = f4[sub + 16]; w = W4[sub + 16]; acc += a.x*w.x + a.y*w.y + a.z*w.z + a.w*w.w;
    a = f4[sub + 32]; w = W4[sub + 32]; acc += a.x*w.x + a.y*w.y + a.z*w.z + a.w*w.w;
    if (sub < 2) { a = f4[48 + sub]; w = W4[48 + sub]; acc += a.x*w.x + a.y*w.y + a.z*w.z + a.w*w.w; }
    #pragma unroll
    for (int off = 8; off > 0; off >>= 1) acc += __shfl_down(acc, off, 16);
    if (sub == 0) h[row] = acc;
}

// h + control-word init (block 0 zeroes the cursors; visible at kernel boundary).
__global__ void k_h(const float* __restrict__ loss, const float* __restrict__ Ws,
                    float* __restrict__ h, unsigned* __restrict__ ctrl, int n) {
    if (blockIdx.x == 0 && threadIdx.x < MAXCOL) ctrl[threadIdx.x] = 0u;
    h_row_body(loss, Ws, h, n, blockIdx.x);
}

// Two-pass scatter, wave-private cursors, block-level reservation:
//   pass 1: per-WAVE LDS histograms.
//   reserve: ONE global atomicAdd per (block,col); per-wave bases by LDS prefix.
//   pass 2: re-read slice (L2-hot), bump wave-private LDS cursor, write entry.
// Stream-count discipline (round-8/9 lesson): SB*NW*ncol = 212K streams
// -> ~1.7MB/XCD of open lines (< L2) -> no write-churn amplification.
// Bucket fill order is nondeterministic; per-column CONTENT is a fixed set ->
// max-reduce is exact and deterministic.
__global__ void k_scatter(const int* __restrict__ src, const int* __restrict__ dst,
                          const float* __restrict__ h, unsigned* __restrict__ ctrl,
                          uint2* __restrict__ buckets, uint2* __restrict__ spill,
                          int ne, int nbin, int epb) {
    __shared__ unsigned cnt[NW * MAXCOL];
    __shared__ unsigned curw[NW * MAXCOL];
    int ncol = 2 * nbin;
    int wv = threadIdx.x >> 6;
    for (int t = threadIdx.x; t < NW * ncol; t += blockDim.x) cnt[t] = 0u;
    __syncthreads();
    int s0 = blockIdx.x * epb, s1 = min(s0 + epb, ne);
    unsigned* myh = cnt + wv * ncol;
    for_each_edge(src, dst, s0, s1, [&](int s, int d) {
        if (s != d) {
            atomicAdd(&myh[d >> ASH], 1u);
            atomicAdd(&myh[nbin + (s >> ASH)], 1u);
        }
    });
    __syncthreads();
    if (threadIdx.x < (unsigned)ncol) {
        int t = threadIdx.x;
        unsigned c[NW], tot = 0;
        #pragma unroll
        for (int w = 0; w < NW; ++w) { c[w] = cnt[w * ncol + t]; tot += c[w]; }
        unsigned base = tot ? atomicAdd(&ctrl[t], tot) : 0u;  // column-local base
        #pragma unroll
        for (int w = 0; w < NW; ++w) { curw[w * ncol + t] = base; base += c[w]; }
    }
    __syncthreads();
    unsigned* myc = curw + wv * ncol;
    for_each_edge(src, dst, s0, s1, [&](int s, int d) {
        if (s != d) {
            unsigned hs = f2ord(h[s]);
            unsigned hd = f2ord(h[d]);
            int c0 = d >> ASH;
            unsigned p0 = atomicAdd(&myc[c0], 1u);
            if (p0 < CAPA) buckets[(size_t)c0 * CAPA + p0] = make_uint2((unsigned)d, hs);
            else { unsigned sp = atomicAdd(&ctrl[MAXCOL - 1], 1u);
                   if (sp < SPILLCAP) spill[sp] = make_uint2((unsigned)d, hs); }
            int c1 = nbin + (s >> ASH);
            unsigned p1 = atomicAdd(&myc[c1], 1u);
            if (p1 < CAPA) buckets[(size_t)c1 * CAPA + p1] = make_uint2((unsigned)s | (1u << 24), hd);
            else { unsigned sp = atomicAdd(&ctrl[MAXCOL - 1], 1u);
                   if (sp < SPILLCAP) spill[sp] = make_uint2((unsigned)s | (1u << 24), hd); }
        }
    });
}

// One WG per (col, ks): stream a 1/AKS slice of the dense column (4 loads in
// flight, 1024 threads), 32KB LDS max, write an ACH-word partial.
__global__ void k_reduce(const uint2* __restrict__ buckets, const unsigned* __restrict__ ctrl,
                         const uint2* __restrict__ spill, unsigned* __restrict__ partials,
                         int nbin) {
    __shared__ unsigned lds[ACH];
    int col = blockIdx.x / AKS, ks = blockIdx.x - col * AKS;
    for (int t = threadIdx.x; t < ACH; t += blockDim.x) lds[t] = 0u;
    __syncthreads();
    unsigned len = min(ctrl[col], CAPA);
    unsigned a = (unsigned)(((unsigned long long)len * ks) / AKS);
    unsigned b = (unsigned)(((unsigned long long)len * (ks + 1)) / AKS);
    const uint2* cb = buckets + (size_t)col * CAPA;
    unsigned i = a + threadIdx.x;
    for (; i + 3u * REDT < b; i += 4u * REDT) {   // 4 independent loads in flight
        uint2 e0 = cb[i];
        uint2 e1 = cb[i + REDT];
        uint2 e2 = cb[i + 2u * REDT];
        uint2 e3 = cb[i + 3u * REDT];
        atomicMax(&lds[e0.x & (ACH - 1)], e0.y);
        atomicMax(&lds[e1.x & (ACH - 1)], e1.y);
        atomicMax(&lds[e2.x & (ACH - 1)], e2.y);
        atomicMax(&lds[e3.x & (ACH - 1)], e3.y);
    }
    for (; i < b; i += REDT) {
        uint2 e = cb[i];
        atomicMax(&lds[e.x & (ACH - 1)], e.y);
    }
    if (ks == 0) {  // spill entries (normally zero)
        unsigned sc = min(ctrl[MAXCOL - 1], (unsigned)SPILLCAP);
        for (unsigned j = threadIdx.x; j < sc; j += blockDim.x) {
            uint2 e = spill[j];
            unsigned node = e.x & 0x00FFFFFFu, dir = e.x >> 24;
            if ((int)(dir * nbin + (node >> ASH)) == col)
                atomicMax(&lds[node & (ACH - 1)], e.y);
        }
    }
    __syncthreads();
    unsigned* outp = partials + (size_t)blockIdx.x * ACH;
    for (int t = threadIdx.x; t < ACH; t += blockDim.x) outp[t] = lds[t];
}

// ---- Fallback: device-scope filtered atomics ----
__global__ void k_edges_dev(const int* __restrict__ src, const int* __restrict__ dst,
                            const float* __restrict__ h, unsigned* __restrict__ partials, int ne) {
    int e = blockIdx.x * blockDim.x + threadIdx.x;
    if (e >= ne) return;
    int s = src[e], d = dst[e];
    if (s == d) return;
    unsigned hs = f2ord(h[s]);
    unsigned hd = f2ord(h[d]);
    unsigned* slot0 = &partials[d];
    unsigned* slot1 = &partials[(1 << 17) + s];
    if (*slot0 < hs) atomicMax(slot0, hs);
    if (*slot1 < hd) atomicMax(slot1, hd);
}

// Fold ks x 2 partials, logit = h + w0*pre + w1*suc (0 == empty -> 0.0 fill),
// block-partial max (fixed RED_BLOCKS grid).
__global__ void k_logit_max(const float* __restrict__ h, const unsigned* __restrict__ partials,
                            const float* __restrict__ Wg, float* __restrict__ logit,
                            float* __restrict__ maxPart, int n, int nbin, int ks, int shift) {
    __shared__ float sm[256];
    float w0 = Wg[0], w1 = Wg[1];
    unsigned mask = (1u << shift) - 1;
    size_t CH = (size_t)1 << shift;
    float m = -INFINITY;
    for (int i = blockIdx.x * 256 + threadIdx.x; i < n; i += 256 * RED_BLOCKS) {
        int chunk = i >> shift, off = i & mask;
        size_t b0 = ((size_t)chunk * ks) * CH + off;
        size_t b1 = ((size_t)(nbin + chunk) * ks) * CH + off;
        unsigned p = 0, s = 0;
        #pragma unroll 4
        for (int k = 0; k < ks; ++k) {
            p = max(p, partials[b0 + (size_t)k * CH]);
            s = max(s, partials[b1 + (size_t)k * CH]);
        }
        float pf = p ? ord2f(p) : 0.0f;
        float sf = s ? ord2f(s) : 0.0f;
        float l = h[i] + w0 * pf + w1 * sf;
        logit[i] = l;
        m = fmaxf(m, l);
    }
    sm[threadIdx.x] = m;
    __syncthreads();
    for (int off = 128; off > 0; off >>= 1) {
        if (threadIdx.x < off) sm[threadIdx.x] = fmaxf(sm[threadIdx.x], sm[threadIdx.x + off]);
        __syncthreads();
    }
    if (threadIdx.x == 0) maxPart[blockIdx.x] = sm[0];
}

__global__ void k_exp_sum(const float* __restrict__ logit, const float* __restrict__ maxPart,
                          float* __restrict__ out, float* __restrict__ sumPart, int n) {
    __shared__ float sm[256];
    sm[threadIdx.x] = maxPart[threadIdx.x];
    __syncthreads();
    for (int off = 128; off > 0; off >>= 1) {
        if (threadIdx.x < off) sm[threadIdx.x] = fmaxf(sm[threadIdx.x], sm[threadIdx.x + off]);
        __syncthreads();
    }
    float gmax = sm[0];
    __syncthreads();
    float acc = 0.0f;
    for (int i = blockIdx.x * 256 + threadIdx.x; i < n; i += 256 * RED_BLOCKS) {
        float e = expf(logit[i] - gmax);
        out[i] = e;
        acc += e;
    }
    sm[threadIdx.x] = acc;
    __syncthreads();
    for (int off = 128; off > 0; off >>= 1) {
        if (threadIdx.x < off) sm[threadIdx.x] += sm[threadIdx.x + off];
        __syncthreads();
    }
    if (threadIdx.x == 0) sumPart[blockIdx.x] = sm[0];
}

__global__ void k_norm(const float* __restrict__ sumPart, float* __restrict__ out, int n) {
    __shared__ float sm[256];
    sm[threadIdx.x] = sumPart[threadIdx.x];
    __syncthreads();
    for (int off = 128; off > 0; off >>= 1) {
        if (threadIdx.x < off) sm[threadIdx.x] += sm[threadIdx.x + off];
        __syncthreads();
    }
    float inv = 1.0f / sm[0];
    for (int i = blockIdx.x * 256 + threadIdx.x; i < n; i += 256 * RED_BLOCKS) out[i] *= inv;
}

extern "C" void kernel_launch(void* const* d_in, const int* in_sizes, int n_in,
                              void* d_out, int out_size, void* d_ws, size_t ws_size,
                              hipStream_t stream) {
    const float* loss = (const float*)d_in[0];   // [N, 200]
    const float* Ws   = (const float*)d_in[1];   // [1, 200]
    const float* Wg   = (const float*)d_in[2];   // [1, 2]
    const int* esrc   = (const int*)d_in[3];     // [E]
    const int* edst   = (const int*)d_in[4];     // [E]
    float* out = (float*)d_out;                  // [N]

    const int n  = in_sizes[0] / 200;
    const int ne = in_sizes[3];
    const int epb = (((ne + SB - 1) / SB) + 3) & ~3;  // edges per block, x4 aligned
    const int Gh  = (n + 15) / 16;

    const int nbin = (n + ACH - 1) >> ASH, ncol = 2 * nbin;

    // ws layout (32-bit words):
    // h[n] | logit[n] | maxPart | sumPart | ctrl[32] | partials[ncol*AKS*ACH] |
    // buckets[ncol*CAPA*2] | spill[SPILLCAP*2]
    float*    h        = (float*)d_ws;
    float*    logit    = h + n;
    float*    maxPart  = logit + n;
    float*    sumPart  = maxPart + RED_BLOCKS;
    unsigned* ctrl     = (unsigned*)(sumPart + RED_BLOCKS);
    unsigned* partials = ctrl + MAXCOL;
    size_t part_w = (size_t)ncol * AKS * ACH;
    uint2*    buckets  = (uint2*)(partials + part_w);
    uint2*    spill    = buckets + (size_t)ncol * CAPA;
    size_t need = ((size_t)2 * n + 2 * RED_BLOCKS + MAXCOL + part_w) * 4
                + ((size_t)ncol * CAPA + SPILLCAP) * 8;

    k_h<<<Gh, 256, 0, stream>>>(loss, Ws, h, ctrl, n);

    if (need <= ws_size && ncol < MAXCOL) {
        k_scatter<<<SB, NT, 0, stream>>>(esrc, edst, h, ctrl, buckets, spill, ne, nbin, epb);
        k_reduce<<<ncol * AKS, REDT, 0, stream>>>(buckets, ctrl, spill, partials, nbin);
        k_logit_max<<<RED_BLOCKS, 256, 0, stream>>>(h, partials, Wg, logit, maxPart, n, nbin, AKS, ASH);
    } else {
        hipMemsetAsync(partials, 0, (size_t)2 * (1 << 17) * 4, stream);
        k_edges_dev<<<(ne + 255) / 256, 256, 0, stream>>>(esrc, edst, h, partials, ne);
        k_logit_max<<<RED_BLOCKS, 256, 0, stream>>>(h, partials, Wg, logit, maxPart, n, 1, 1, 17);
    }

    k_exp_sum<<<RED_BLOCKS, 256, 0, stream>>>(logit, maxPart, out, sumPart, n);
    k_norm<<<RED_BLOCKS, 256, 0, stream>>>(sumPart, out, n);
}